// Round 12
// baseline (2622.317 us; speedup 1.0000x reference)
//
#include <hip/hip_runtime.h>
#include <math.h>

// TTT recurrence: one wave (64 lanes) per row, lane = hidden index.
// R5: W2 as packed f16 pairs, v_dot2_f32_f16 matvecs, f16 LDS broadcasts,
//     final-forward reuse as next gs0 forward.
// R7: fast_tanh (exp2+rcp), DPP wave reduction for the head.
// R8: no hot-loop barriers (single wave, DS in-order).
// R11: merged BWD->FWD phases; dz-shadow = {scalar updates + w2r apply},
//     h1-shadow = {w2c updates}; incremental z1; W1/b1 materialized per step.
// R12: (1) dz pairs cached in registers (dzr[8], stashed in the d-sums loop)
// so the w2c update does NO LDS reads — its 8 ds_read_b128 were entering the
// in-order DS queue AHEAD of the a-sums' dependent s_h1h reads, adding ~100cyc
// to the critical path. Only structural LDS remains: 2 broadcast write+read.
// (2) 8 accumulators in both dot loops (same instrs, half the chain depth).

#define TT  784
#define HH  64
#define LR  0.01f

typedef _Float16 h2v __attribute__((ext_vector_type(2)));
#define FDOT2(a, b, c) __builtin_amdgcn_fdot2((a), (b), (c), false)
#define BC(f) __builtin_bit_cast(h2v, (f))

// tanh(x) = 1 - 2/(exp2(2*log2e*x)+1); saturates exactly at +-1.
__device__ __forceinline__ float fast_tanh(float x) {
    float e = __builtin_amdgcn_exp2f(x * 2.885390081777926814f);
    float r = __builtin_amdgcn_rcpf(e + 1.0f);
    return fmaf(-2.0f, r, 1.0f);
}

template <int CTRL, int RMASK, bool BC_>
__device__ __forceinline__ float dpp_add(float x) {
    int t = __builtin_amdgcn_update_dpp(0, __builtin_bit_cast(int, x),
                                        CTRL, RMASK, 0xf, BC_);
    return x + __builtin_bit_cast(float, t);
}

// Full wave64 sum -> uniform value (DPP reduce, total in lane 63).
__device__ __forceinline__ float wave_sum(float x) {
    x = dpp_add<0x111, 0xf, true>(x);   // row_shr:1
    x = dpp_add<0x112, 0xf, true>(x);   // row_shr:2
    x = dpp_add<0x114, 0xf, true>(x);   // row_shr:4
    x = dpp_add<0x118, 0xf, true>(x);   // row_shr:8
    x = dpp_add<0x142, 0xa, false>(x);  // row_bcast:15 -> rows 1,3
    x = dpp_add<0x143, 0xc, false>(x);  // row_bcast:31 -> rows 2,3
    return __builtin_bit_cast(float,
        __builtin_amdgcn_readlane(__builtin_bit_cast(int, x), 63));
}

__global__ __launch_bounds__(64, 2)
void ttt_kernel(const float* __restrict__ ts,
                const float* __restrict__ xs,
                const int*   __restrict__ mask,
                const float* __restrict__ W1,
                const float* __restrict__ b1,
                const float* __restrict__ W2,
                const float* __restrict__ b2,
                const float* __restrict__ W3,
                const float* __restrict__ b3,
                float* __restrict__ out)
{
    __shared__ __align__(16) _Float16 s_h1h[HH];   // h1 broadcast, f16
    __shared__ __align__(16) _Float16 s_dzh[HH];   // dz2 broadcast, f16
    __shared__ float s_ts[TT];
    __shared__ float s_xs[TT];
    __shared__ int   s_mask[TT - 1];

    const int row  = blockIdx.x;
    const int lane = threadIdx.x;  // 0..63

    for (int i = lane; i < TT; i += HH) {
        s_ts[i] = ts[i];
        s_xs[i] = xs[row * TT + i];
    }
    for (int i = lane; i < TT - 1; i += HH) s_mask[i] = mask[row * (TT - 1) + i];

    // Per-lane theta (f32 except W2 storage).
    float w1a = W1[2 * lane + 0];
    float w1b = W1[2 * lane + 1];
    float b1v = b1[lane];
    float b2v = b2[lane];
    float w3v = W3[lane];
    float b3v = b3[0];

    h2v w2r[HH / 2];  // (W2[lane][2k], W2[lane][2k+1])
    h2v w2c[HH / 2];  // (W2[2k][lane], W2[2k+1][lane])
#pragma unroll
    for (int k = 0; k < HH / 2; ++k) {
        w2r[k] = h2v{(_Float16)W2[lane * HH + 2 * k], (_Float16)W2[lane * HH + 2 * k + 1]};
        w2c[k] = h2v{(_Float16)W2[(2 * k) * HH + lane], (_Float16)W2[(2 * k + 1) * HH + lane]};
    }
    __syncthreads();  // one-time (staging); outside hot loop

    const float4* h1v4 = (const float4*)s_h1h;  // 8 float4 = 64 f16
    const float4* dzv4 = (const float4*)s_dzh;

    float t_prev = s_ts[0];
    const float x0 = s_xs[0];
    float x_hat  = x0;
    float x_prev = x0;
    if (lane == 0) out[row * TT] = x0;

    float4 hr[8];            // h1 pairs — live across phases
    float  h1f, h2f, predf;  // own-lane h1, h2; uniform pred
    float  z1f;              // current z1 (incremental inside gs loop)
    float  sdz1 = 0.f;       // per-step sum of dz1
    float  tc = 0.f, x_true = 0.f, tin = 0.f, nls = 0.f;

    // Forward a-sums from current h1f (already tanh'ed): pre-loop stash only.
    auto FWD_TAIL = [&]() {
        float a0 = 0.f, a1 = 0.f, a2 = 0.f, a3 = 0.f;
#pragma unroll
        for (int k = 0; k < 8; ++k) {
            float4 q = h1v4[k];          // broadcast read (uniform addr)
            hr[k] = q;
            a0 = FDOT2(w2r[4 * k + 0], BC(q.x), a0);
            a1 = FDOT2(w2r[4 * k + 1], BC(q.y), a1);
            a2 = FDOT2(w2r[4 * k + 2], BC(q.z), a2);
            a3 = FDOT2(w2r[4 * k + 3], BC(q.w), a3);
        }
        float z2 = ((a0 + a1) + (a2 + a3)) + b2v;
        h2f = fast_tanh(z2);
        predf = wave_sum(w3v * h2f) + b3v;
    };

    // Merged phase: BWD of the current pred, then the next forward.
    auto MERGED = [&](float xt, bool final_) {
        // ---- backward (gradients from current/old theta)
        const float dl   = 2.0f * (predf - xt);
        const float dz2s = dl * w3v * (1.0f - h2f * h2f);   // OLD w3
        s_dzh[lane] = (_Float16)dz2s;
        // dz write->read shadow: scalar updates + batched w2r apply (old hr)
        w3v = fmaf(-LR * dl, h2f, w3v);
        b3v -= LR * dl;
        b2v -= LR * dz2s;
        const _Float16 sd = (_Float16)(-LR * dz2s);
        const h2v sdv = h2v{sd, sd};
        const _Float16 sh = (_Float16)(-LR * h1f);          // OLD h1 (own lane)
        const h2v shv = h2v{sh, sh};
#pragma unroll
        for (int k = 0; k < 8; ++k) {
            float4 o = hr[k];            // OLD h1 pairs (register-resident)
            w2r[4 * k + 0] += sdv * BC(o.x);
            w2r[4 * k + 1] += sdv * BC(o.y);
            w2r[4 * k + 2] += sdv * BC(o.z);
            w2r[4 * k + 3] += sdv * BC(o.w);
        }
        // d-sums on OLD w2c; cache dz pairs in registers (dzr) for the
        // update loop so it needs NO LDS reads (keeps the in-order DS queue
        // clear for the a-sums' dependent s_h1h reads).
        float4 dzr[8];
        float d0 = 0.f, d1 = 0.f, d2 = 0.f, d3 = 0.f;
        float d4 = 0.f, d5 = 0.f, d6 = 0.f, d7 = 0.f;
#pragma unroll
        for (int k = 0; k < 8; ++k) {
            float4 q = dzv4[k];          // broadcast read (own-wave ordered)
            dzr[k] = q;
            if (k & 1) {
                d4 = FDOT2(w2c[4 * k + 0], BC(q.x), d4);
                d5 = FDOT2(w2c[4 * k + 1], BC(q.y), d5);
                d6 = FDOT2(w2c[4 * k + 2], BC(q.z), d6);
                d7 = FDOT2(w2c[4 * k + 3], BC(q.w), d7);
            } else {
                d0 = FDOT2(w2c[4 * k + 0], BC(q.x), d0);
                d1 = FDOT2(w2c[4 * k + 1], BC(q.y), d1);
                d2 = FDOT2(w2c[4 * k + 2], BC(q.z), d2);
                d3 = FDOT2(w2c[4 * k + 3], BC(q.w), d3);
            }
        }
        const float dh1 = (((d0 + d1) + (d2 + d3)) + ((d4 + d5) + (d6 + d7)));
        const float dz1 = dh1 * (1.0f - h1f * h1f);
        sdz1 += dz1;
        // ---- next forward's z1 (+ materialization on the final phase)
        if (!final_) {
            z1f = fmaf(nls, dz1, z1f);   // exact: inputs fixed over gs loop
        } else {
            w1a = fmaf(-LR * tc,     sdz1, w1a);
            w1b = fmaf(-LR * x_prev, sdz1, w1b);
            b1v = fmaf(-LR,          sdz1, b1v);
            z1f = fmaf(w1a, tin, fmaf(w1b, x_true, b1v));
        }
        h1f = fast_tanh(z1f);
        s_h1h[lane] = (_Float16)h1f;
        // h1 write->read shadow: batched w2c updates from dzr (pure VALU)
#pragma unroll
        for (int k = 0; k < 8; ++k) {
            float4 q = dzr[k];
            w2c[4 * k + 0] += shv * BC(q.x);
            w2c[4 * k + 1] += shv * BC(q.y);
            w2c[4 * k + 2] += shv * BC(q.z);
            w2c[4 * k + 3] += shv * BC(q.w);
        }
        // ---- forward a-sums on updated w2r
        float a0 = 0.f, a1 = 0.f, a2 = 0.f, a3 = 0.f;
        float a4 = 0.f, a5 = 0.f, a6 = 0.f, a7 = 0.f;
#pragma unroll
        for (int k = 0; k < 8; ++k) {
            float4 q = h1v4[k];          // broadcast read
            hr[k] = q;                   // NEW h1 pairs
            if (k & 1) {
                a4 = FDOT2(w2r[4 * k + 0], BC(q.x), a4);
                a5 = FDOT2(w2r[4 * k + 1], BC(q.y), a5);
                a6 = FDOT2(w2r[4 * k + 2], BC(q.z), a6);
                a7 = FDOT2(w2r[4 * k + 3], BC(q.w), a7);
            } else {
                a0 = FDOT2(w2r[4 * k + 0], BC(q.x), a0);
                a1 = FDOT2(w2r[4 * k + 1], BC(q.y), a1);
                a2 = FDOT2(w2r[4 * k + 2], BC(q.z), a2);
                a3 = FDOT2(w2r[4 * k + 3], BC(q.w), a3);
            }
        }
        float z2 = (((a0 + a1) + (a2 + a3)) + ((a4 + a5) + (a6 + a7))) + b2v;
        h2f = fast_tanh(z2);
        predf = wave_sum(w3v * h2f) + b3v;
    };

    // Pre-loop stash: theta0 forward at (ts[1], x0) = t=1's gs0 forward.
    z1f = fmaf(w1a, s_ts[1], fmaf(w1b, x0, b1v));
    h1f = fast_tanh(z1f);
    s_h1h[lane] = (_Float16)h1f;
    FWD_TAIL();

    for (int t = 1; t < TT; ++t) {
        tc     = s_ts[t];
        x_true = s_xs[t];
        tin    = tc + (tc - t_prev);
        nls    = -LR * fmaf(tc, tc, fmaf(x_prev, x_prev, 1.0f));
        const float x_t = s_mask[t - 1] ? x_true : x_hat;   // teacher forcing

        sdz1 = 0.f;
        MERGED(x_t, false);   // BWD gs0 (stash fwd) + FWD gs1
        MERGED(x_t, false);   // BWD gs1 + FWD gs2
        MERGED(x_t, false);   // BWD gs2 + FWD gs3
        MERGED(x_t, true);    // BWD gs3 + final forward (t+1's gs0 stash)
        x_hat = predf;

        if (lane == 0) out[row * TT + t] = x_hat;
        t_prev = tc;
        x_prev = x_true;
    }
}

extern "C" void kernel_launch(void* const* d_in, const int* in_sizes, int n_in,
                              void* d_out, int out_size, void* d_ws, size_t ws_size,
                              hipStream_t stream) {
    const float* ts   = (const float*)d_in[0];
    const float* xs   = (const float*)d_in[1];
    const int*   mask = (const int*)d_in[2];
    const float* W1   = (const float*)d_in[3];
    const float* b1   = (const float*)d_in[4];
    const float* W2   = (const float*)d_in[5];
    const float* b2   = (const float*)d_in[6];
    const float* W3   = (const float*)d_in[7];
    const float* b3   = (const float*)d_in[8];
    float* out = (float*)d_out;

    const int B = in_sizes[1] / TT;  // 2048
    dim3 grid(B), block(HH);
    hipLaunchKernelGGL(ttt_kernel, grid, block, 0, stream,
                       ts, xs, mask, W1, b1, W2, b2, W3, b3, out);
}

// Round 13
// 2517.524 us; speedup vs baseline: 1.0416x; 1.0416x over previous
//
#include <hip/hip_runtime.h>
#include <math.h>

// TTT recurrence: one wave (64 lanes) per row, lane = hidden index.
// R5: W2 as packed f16 pairs, v_dot2_f32_f16 matvecs, f16 LDS broadcasts,
//     final-forward reuse as next gs0 forward.
// R7: fast_tanh (exp2+rcp), DPP wave reduction for the head.
// R8: no hot-loop barriers (single wave, DS in-order).
// R11: merged BWD->FWD phases; dz-shadow = {scalar updates + w2r apply},
//     h1-shadow = {w2c updates}; incremental z1; W1/b1 materialized per step.
// R12 (reverted): dzr register-caching + 8-acc split — compiler kept VGPR=92
//     (defeated the caching) and added moves; +4%. R13 = R11 verbatim.
//     Lesson: R11's batched-block structure is the compiler's local optimum;
//     source-level scheduling perturbations (R10, R12) only add instructions.

#define TT  784
#define HH  64
#define LR  0.01f

typedef _Float16 h2v __attribute__((ext_vector_type(2)));
#define FDOT2(a, b, c) __builtin_amdgcn_fdot2((a), (b), (c), false)
#define BC(f) __builtin_bit_cast(h2v, (f))

// tanh(x) = 1 - 2/(exp2(2*log2e*x)+1); saturates exactly at +-1.
__device__ __forceinline__ float fast_tanh(float x) {
    float e = __builtin_amdgcn_exp2f(x * 2.885390081777926814f);
    float r = __builtin_amdgcn_rcpf(e + 1.0f);
    return fmaf(-2.0f, r, 1.0f);
}

template <int CTRL, int RMASK, bool BC_>
__device__ __forceinline__ float dpp_add(float x) {
    int t = __builtin_amdgcn_update_dpp(0, __builtin_bit_cast(int, x),
                                        CTRL, RMASK, 0xf, BC_);
    return x + __builtin_bit_cast(float, t);
}

// Full wave64 sum -> uniform value (DPP reduce, total in lane 63).
__device__ __forceinline__ float wave_sum(float x) {
    x = dpp_add<0x111, 0xf, true>(x);   // row_shr:1
    x = dpp_add<0x112, 0xf, true>(x);   // row_shr:2
    x = dpp_add<0x114, 0xf, true>(x);   // row_shr:4
    x = dpp_add<0x118, 0xf, true>(x);   // row_shr:8
    x = dpp_add<0x142, 0xa, false>(x);  // row_bcast:15 -> rows 1,3
    x = dpp_add<0x143, 0xc, false>(x);  // row_bcast:31 -> rows 2,3
    return __builtin_bit_cast(float,
        __builtin_amdgcn_readlane(__builtin_bit_cast(int, x), 63));
}

__global__ __launch_bounds__(64, 2)
void ttt_kernel(const float* __restrict__ ts,
                const float* __restrict__ xs,
                const int*   __restrict__ mask,
                const float* __restrict__ W1,
                const float* __restrict__ b1,
                const float* __restrict__ W2,
                const float* __restrict__ b2,
                const float* __restrict__ W3,
                const float* __restrict__ b3,
                float* __restrict__ out)
{
    __shared__ __align__(16) _Float16 s_h1h[HH];   // h1 broadcast, f16
    __shared__ __align__(16) _Float16 s_dzh[HH];   // dz2 broadcast, f16
    __shared__ float s_ts[TT];
    __shared__ float s_xs[TT];
    __shared__ int   s_mask[TT - 1];

    const int row  = blockIdx.x;
    const int lane = threadIdx.x;  // 0..63

    for (int i = lane; i < TT; i += HH) {
        s_ts[i] = ts[i];
        s_xs[i] = xs[row * TT + i];
    }
    for (int i = lane; i < TT - 1; i += HH) s_mask[i] = mask[row * (TT - 1) + i];

    // Per-lane theta (f32 except W2 storage).
    float w1a = W1[2 * lane + 0];
    float w1b = W1[2 * lane + 1];
    float b1v = b1[lane];
    float b2v = b2[lane];
    float w3v = W3[lane];
    float b3v = b3[0];

    h2v w2r[HH / 2];  // (W2[lane][2k], W2[lane][2k+1])
    h2v w2c[HH / 2];  // (W2[2k][lane], W2[2k+1][lane])
#pragma unroll
    for (int k = 0; k < HH / 2; ++k) {
        w2r[k] = h2v{(_Float16)W2[lane * HH + 2 * k], (_Float16)W2[lane * HH + 2 * k + 1]};
        w2c[k] = h2v{(_Float16)W2[(2 * k) * HH + lane], (_Float16)W2[(2 * k + 1) * HH + lane]};
    }
    __syncthreads();  // one-time (staging); outside hot loop

    const float4* h1v4 = (const float4*)s_h1h;  // 8 float4 = 64 f16
    const float4* dzv4 = (const float4*)s_dzh;

    float t_prev = s_ts[0];
    const float x0 = s_xs[0];
    float x_hat  = x0;
    float x_prev = x0;
    if (lane == 0) out[row * TT] = x0;

    float4 hr[8];            // h1 pairs — live across phases
    float  h1f, h2f, predf;  // own-lane h1, h2; uniform pred
    float  z1f;              // current z1 (incremental inside gs loop)
    float  sdz1 = 0.f;       // per-step sum of dz1
    float  tc = 0.f, x_true = 0.f, tin = 0.f, nls = 0.f;

    // Forward a-sums from current h1f (already tanh'ed): pre-loop stash only.
    auto FWD_TAIL = [&]() {
        float a0 = 0.f, a1 = 0.f, a2 = 0.f, a3 = 0.f;
#pragma unroll
        for (int k = 0; k < 8; ++k) {
            float4 q = h1v4[k];          // broadcast read (uniform addr)
            hr[k] = q;
            a0 = FDOT2(w2r[4 * k + 0], BC(q.x), a0);
            a1 = FDOT2(w2r[4 * k + 1], BC(q.y), a1);
            a2 = FDOT2(w2r[4 * k + 2], BC(q.z), a2);
            a3 = FDOT2(w2r[4 * k + 3], BC(q.w), a3);
        }
        float z2 = ((a0 + a1) + (a2 + a3)) + b2v;
        h2f = fast_tanh(z2);
        predf = wave_sum(w3v * h2f) + b3v;
    };

    // Merged phase: BWD of the current pred, then the next forward.
    // final_=true: next forward is the adapted-theta prediction forward
    // (z1 re-grounded from materialized W1/b1 at (tin, x_true)).
    auto MERGED = [&](float xt, bool final_) {
        // ---- backward (gradients from current/old theta)
        const float dl   = 2.0f * (predf - xt);
        const float dz2s = dl * w3v * (1.0f - h2f * h2f);   // OLD w3
        s_dzh[lane] = (_Float16)dz2s;
        // dz write->read shadow: scalar updates + batched w2r apply (old hr)
        w3v = fmaf(-LR * dl, h2f, w3v);
        b3v -= LR * dl;
        b2v -= LR * dz2s;
        const _Float16 sd = (_Float16)(-LR * dz2s);
        const h2v sdv = h2v{sd, sd};
        const _Float16 sh = (_Float16)(-LR * h1f);          // OLD h1 (own lane)
        const h2v shv = h2v{sh, sh};
#pragma unroll
        for (int k = 0; k < 8; ++k) {
            float4 o = hr[k];            // OLD h1 pairs (register-resident)
            w2r[4 * k + 0] += sdv * BC(o.x);
            w2r[4 * k + 1] += sdv * BC(o.y);
            w2r[4 * k + 2] += sdv * BC(o.z);
            w2r[4 * k + 3] += sdv * BC(o.w);
        }
        // d-sums on OLD w2c
        float d0 = 0.f, d1 = 0.f, d2 = 0.f, d3 = 0.f;
#pragma unroll
        for (int k = 0; k < 8; ++k) {
            float4 q = dzv4[k];          // broadcast read (own-wave ordered)
            d0 = FDOT2(w2c[4 * k + 0], BC(q.x), d0);
            d1 = FDOT2(w2c[4 * k + 1], BC(q.y), d1);
            d2 = FDOT2(w2c[4 * k + 2], BC(q.z), d2);
            d3 = FDOT2(w2c[4 * k + 3], BC(q.w), d3);
        }
        const float dh1 = (d0 + d1) + (d2 + d3);
        const float dz1 = dh1 * (1.0f - h1f * h1f);
        sdz1 += dz1;
        // ---- next forward's z1 (+ materialization on the final phase)
        if (!final_) {
            z1f = fmaf(nls, dz1, z1f);   // exact: inputs fixed over gs loop
        } else {
            w1a = fmaf(-LR * tc,     sdz1, w1a);
            w1b = fmaf(-LR * x_prev, sdz1, w1b);
            b1v = fmaf(-LR,          sdz1, b1v);
            z1f = fmaf(w1a, tin, fmaf(w1b, x_true, b1v));
        }
        h1f = fast_tanh(z1f);
        s_h1h[lane] = (_Float16)h1f;
        // h1 write->read shadow: batched w2c updates (re-read s_dzh)
#pragma unroll
        for (int k = 0; k < 8; ++k) {
            float4 q = dzv4[k];
            w2c[4 * k + 0] += shv * BC(q.x);
            w2c[4 * k + 1] += shv * BC(q.y);
            w2c[4 * k + 2] += shv * BC(q.z);
            w2c[4 * k + 3] += shv * BC(q.w);
        }
        // ---- forward a-sums on updated w2r
        float a0 = 0.f, a1 = 0.f, a2 = 0.f, a3 = 0.f;
#pragma unroll
        for (int k = 0; k < 8; ++k) {
            float4 q = h1v4[k];          // broadcast read
            hr[k] = q;                   // NEW h1 pairs
            a0 = FDOT2(w2r[4 * k + 0], BC(q.x), a0);
            a1 = FDOT2(w2r[4 * k + 1], BC(q.y), a1);
            a2 = FDOT2(w2r[4 * k + 2], BC(q.z), a2);
            a3 = FDOT2(w2r[4 * k + 3], BC(q.w), a3);
        }
        float z2 = ((a0 + a1) + (a2 + a3)) + b2v;
        h2f = fast_tanh(z2);
        predf = wave_sum(w3v * h2f) + b3v;
    };

    // Pre-loop stash: theta0 forward at (ts[1], x0) = t=1's gs0 forward.
    z1f = fmaf(w1a, s_ts[1], fmaf(w1b, x0, b1v));
    h1f = fast_tanh(z1f);
    s_h1h[lane] = (_Float16)h1f;
    FWD_TAIL();

    for (int t = 1; t < TT; ++t) {
        tc     = s_ts[t];
        x_true = s_xs[t];
        tin    = tc + (tc - t_prev);
        nls    = -LR * fmaf(tc, tc, fmaf(x_prev, x_prev, 1.0f));
        const float x_t = s_mask[t - 1] ? x_true : x_hat;   // teacher forcing

        sdz1 = 0.f;
        MERGED(x_t, false);   // BWD gs0 (stash fwd) + FWD gs1
        MERGED(x_t, false);   // BWD gs1 + FWD gs2
        MERGED(x_t, false);   // BWD gs2 + FWD gs3
        MERGED(x_t, true);    // BWD gs3 + final forward (t+1's gs0 stash)
        x_hat = predf;

        if (lane == 0) out[row * TT + t] = x_hat;
        t_prev = tc;
        x_prev = x_true;
    }
}

extern "C" void kernel_launch(void* const* d_in, const int* in_sizes, int n_in,
                              void* d_out, int out_size, void* d_ws, size_t ws_size,
                              hipStream_t stream) {
    const float* ts   = (const float*)d_in[0];
    const float* xs   = (const float*)d_in[1];
    const int*   mask = (const int*)d_in[2];
    const float* W1   = (const float*)d_in[3];
    const float* b1   = (const float*)d_in[4];
    const float* W2   = (const float*)d_in[5];
    const float* b2   = (const float*)d_in[6];
    const float* W3   = (const float*)d_in[7];
    const float* b3   = (const float*)d_in[8];
    float* out = (float*)d_out;

    const int B = in_sizes[1] / TT;  // 2048
    dim3 grid(B), block(HH);
    hipLaunchKernelGGL(ttt_kernel, grid, block, 0, stream,
                       ts, xs, mask, W1, b1, W2, b2, W3, b3, out);
}